// Round 5
// baseline (6046.653 us; speedup 1.0000x reference)
//
#include <hip/hip_runtime.h>
#include <hip/hip_cooperative_groups.h>
#include <math.h>

namespace cg = cooperative_groups;

#define NB 8
#define NN 1024
#define NC 128
#define INV_TAU (1.0f/0.3f)
#define LOG2E 1.44269504088896340736f
#define SINK_EPS 2e-4f

__device__ __forceinline__ float wsum(float v){
  #pragma unroll
  for (int o = 32; o > 0; o >>= 1) v += __shfl_xor(v, o, 64);
  return v;
}
__device__ __forceinline__ float wmax(float v){
  #pragma unroll
  for (int o = 32; o > 0; o >>= 1) v = fmaxf(v, __shfl_xor(v, o, 64));
  return v;
}
__device__ __forceinline__ float fexp2(float x){ return __builtin_amdgcn_exp2f(x); }
__device__ __forceinline__ float flog2(float x){ return __builtin_amdgcn_logf(x); }

// load 16 floats for this lane's j-slots: j = 8*lane..+8 and 512+8*lane..+8
__device__ __forceinline__ void load16(const float* __restrict__ base, int lane, float* o){
  float4 a = *(const float4*)(base + 8 * lane);
  float4 b = *(const float4*)(base + 8 * lane + 4);
  float4 c = *(const float4*)(base + 512 + 8 * lane);
  float4 d = *(const float4*)(base + 512 + 8 * lane + 4);
  o[0]=a.x; o[1]=a.y; o[2]=a.z; o[3]=a.w; o[4]=b.x; o[5]=b.y; o[6]=b.z; o[7]=b.w;
  o[8]=c.x; o[9]=c.y; o[10]=c.z; o[11]=c.w; o[12]=d.x; o[13]=d.y; o[14]=d.z; o[15]=d.w;
}

// accs: [0:16) loss | [16:32) lc | [32:48) perm | [48:64) cm | [64:80) gmax | 80 IQ2 | [96:126) sink deltas
__global__ void k_init(float* accs, float* V){
  int i = blockIdx.x * 256 + threadIdx.x;   // grid 32 x 256 = 8192
  if (i < 128) accs[i] = 0.0f;
  V[i] = 0.0f;
}

// ---- L2 normalize * 20 over C; feats[16,1024,128] -> f1 = rows 0::2, f2 = 1::2
__global__ void k_normalize(const float* __restrict__ feats,
                            float* __restrict__ f1, float* __restrict__ f2){
  int vid = blockIdx.x;
  int lane = threadIdx.x;          // 64 threads, 2 floats each
  const float* src = feats + (size_t)vid * NC;
  float2 x = *(const float2*)(src + lane * 2);
  float s = wsum(x.x * x.x + x.y * x.y);
  float sc = 20.0f / fmaxf(sqrtf(s), 1e-12f);
  int batch = vid >> 10, n = vid & 1023;
  float* dst = ((batch & 1) ? f2 : f1) + ((size_t)(batch >> 1) * NN + n) * NC;
  float2 y; y.x = x.x * sc; y.y = x.y * sc;
  *(float2*)(dst + lane * 2) = y;
}

// ---- C[b] = A[b] (1024x128) * B[(b+rollB)&7]^T -> [1024x1024]
__global__ __launch_bounds__(256) void k_gemm_bt(const float* __restrict__ A,
                                                 const float* __restrict__ A2,
                                                 const float* __restrict__ Bm,
                                                 void* __restrict__ Cm,
                                                 int rollB, int addA, int q16){
  __shared__ float As[64][68];
  __shared__ float Bs[64][68];
  const float QS12 = 32766.0f / 400.0f;
  int b = blockIdx.z;
  int n0 = blockIdx.y * 64, m0 = blockIdx.x * 64;
  const float* Ab  = A  + (size_t)b * NN * NC;
  const float* A2b = A2 + (size_t)b * NN * NC;
  const float* Bb  = Bm + (size_t)((b + rollB) & 7) * NN * NC;
  int tid = threadIdx.x;
  int ty = tid >> 4, tx = tid & 15;
  float acc[4][4] = {};
  for (int kk = 0; kk < NC; kk += 64){
    #pragma unroll
    for (int i = 0; i < 4; i++){
      int t = tid + 256 * i;
      int r = t >> 4, k4 = t & 15;
      float4 va = *(const float4*)(Ab + (size_t)(n0 + r) * NC + kk + k4 * 4);
      if (addA){
        float4 v2 = *(const float4*)(A2b + (size_t)(n0 + r) * NC + kk + k4 * 4);
        va.x += v2.x; va.y += v2.y; va.z += v2.z; va.w += v2.w;
      }
      As[k4*4+0][r] = va.x; As[k4*4+1][r] = va.y; As[k4*4+2][r] = va.z; As[k4*4+3][r] = va.w;
      float4 vb = *(const float4*)(Bb + (size_t)(m0 + r) * NC + kk + k4 * 4);
      Bs[k4*4+0][r] = vb.x; Bs[k4*4+1][r] = vb.y; Bs[k4*4+2][r] = vb.z; Bs[k4*4+3][r] = vb.w;
    }
    __syncthreads();
    #pragma unroll 8
    for (int k = 0; k < 64; k++){
      float4 a4 = *(const float4*)&As[k][ty * 4];
      float4 b4 = *(const float4*)&Bs[k][tx * 4];
      acc[0][0] += a4.x*b4.x; acc[0][1] += a4.x*b4.y; acc[0][2] += a4.x*b4.z; acc[0][3] += a4.x*b4.w;
      acc[1][0] += a4.y*b4.x; acc[1][1] += a4.y*b4.y; acc[1][2] += a4.y*b4.z; acc[1][3] += a4.y*b4.w;
      acc[2][0] += a4.z*b4.x; acc[2][1] += a4.z*b4.y; acc[2][2] += a4.z*b4.z; acc[2][3] += a4.z*b4.w;
      acc[3][0] += a4.w*b4.x; acc[3][1] += a4.w*b4.y; acc[3][2] += a4.w*b4.z; acc[3][3] += a4.w*b4.w;
    }
    __syncthreads();
  }
  if (q16){
    short* Cb = (short*)Cm + (size_t)b * NN * NN;
    #pragma unroll
    for (int i = 0; i < 4; i++){
      int qv[4];
      #pragma unroll
      for (int j = 0; j < 4; j++){
        float q = rintf(fminf(fmaxf(acc[i][j] * QS12, -32766.0f), 32766.0f));
        qv[j] = (int)q;
      }
      int2 w;
      w.x = (qv[0] & 0xFFFF) | (qv[1] << 16);
      w.y = (qv[2] & 0xFFFF) | (qv[3] << 16);
      *(int2*)(Cb + (size_t)(n0 + ty * 4 + i) * NN + m0 + tx * 4) = w;
    }
  } else {
    float* Cb = (float*)Cm + (size_t)b * NN * NN;
    #pragma unroll
    for (int i = 0; i < 4; i++){
      float4 o = make_float4(acc[i][0], acc[i][1], acc[i][2], acc[i][3]);
      *(float4*)(Cb + (size_t)(n0 + ty * 4 + i) * NN + m0 + tx * 4) = o;
    }
  }
}

// ---- per-row logsumexp (nat domain, for k_fva)
__global__ void k_rowstats(const float* __restrict__ Mb, float* __restrict__ lse){
  int row = blockIdx.x * 4 + (threadIdx.x >> 6);
  int lane = threadIdx.x & 63;
  const float* p = Mb + (size_t)row * NN;
  float x[16]; float mx = -3.402823466e38f;
  #pragma unroll
  for (int k = 0; k < 16; k++){ x[k] = p[lane + 64 * k]; mx = fmaxf(mx, x[k]); }
  mx = wmax(mx);
  float s = 0.0f;
  #pragma unroll
  for (int k = 0; k < 16; k++) s += expf(x[k] - mx);
  s = wsum(s);
  if (lane == 0) lse[row] = mx + logf(s);
}

// ---- row stats (nat) + argmax + correct_match + global absmax
__global__ void k_rowstats_argmax(const float* __restrict__ Mb, float* __restrict__ lse,
                                  float* __restrict__ accs){
  __shared__ float axs[4];
  int row = blockIdx.x * 4 + (threadIdx.x >> 6);
  int wid = threadIdx.x >> 6;
  int lane = threadIdx.x & 63;
  const float* p = Mb + (size_t)row * NN;
  float x[16]; float mx = -3.402823466e38f; float ax = 0.0f;
  float bm = -3.402823466e38f; int bi = 0;
  #pragma unroll
  for (int k = 0; k < 16; k++){
    x[k] = p[lane + 64 * k];
    mx = fmaxf(mx, x[k]);
    ax = fmaxf(ax, fabsf(x[k]));
    if (x[k] > bm){ bm = x[k]; bi = lane + 64 * k; }
  }
  mx = wmax(mx); ax = wmax(ax);
  #pragma unroll
  for (int o = 32; o > 0; o >>= 1){
    float om = __shfl_xor(bm, o, 64); int oi = __shfl_xor(bi, o, 64);
    if (om > bm || (om == bm && oi < bi)){ bm = om; bi = oi; }
  }
  float s = 0.0f;
  #pragma unroll
  for (int k = 0; k < 16; k++) s += expf(x[k] - mx);
  s = wsum(s);
  if (lane == 0){
    lse[row] = mx + logf(s);
    axs[wid] = ax;
    if (bi == (row & 1023)) atomicAdd(&accs[48 + (blockIdx.x & 15)], 1.0f);
  }
  __syncthreads();
  if (threadIdx.x == 0){
    float a = fmaxf(fmaxf(axs[0], axs[1]), fmaxf(axs[2], axs[3]));
    atomicMax((int*)&accs[64 + (blockIdx.x & 15)], __float_as_int(a));
  }
}

// ---- quantization scale: L2 = M*INV_TAU*LOG2E quantized to +-32766
__global__ void k_scale(float* accs){
  if (threadIdx.x == 0){
    float g = 0.0f;
    for (int j = 0; j < 16; j++) g = fmaxf(g, accs[64 + j]);
    accs[80] = (g * INV_TAU * LOG2E) / 32766.0f;   // IQ2
  }
}

// ---- fva_half[z][b,n,c] = sum_{m in half z} exp(M[b,n,m]-lse1[b,n]) * f1[(b+1)&7][m][c]
__global__ __launch_bounds__(256) void k_fva(const float* __restrict__ Mb,
                                             const float* __restrict__ lse1,
                                             const float* __restrict__ f1,
                                             float* __restrict__ fva){
  __shared__ float Ps[64][36];
  __shared__ float Bs[64][128];
  int b = blockIdx.y;
  int z = blockIdx.z;
  int n0 = blockIdx.x * 32;
  int mbase = z * 512;
  const float* Mrow = Mb + (size_t)(b * NN + n0) * NN + mbase;
  const float* fa = f1 + (size_t)((b + 1) & 7) * NN * NC + (size_t)mbase * NC;
  const float* lseb = lse1 + b * NN + n0;
  float* fvaH = fva + (size_t)z * 1048576;
  int tid = threadIdx.x;
  int ty = tid >> 5, tx = tid & 31;
  float acc[4][4] = {};
  for (int mm = 0; mm < 512; mm += 64){
    #pragma unroll
    for (int i = 0; i < 2; i++){
      int t = tid + 256 * i;
      int r = t >> 4, m4 = t & 15;
      float l = lseb[r];
      float4 v = *(const float4*)(Mrow + (size_t)r * NN + mm + m4 * 4);
      Ps[m4*4+0][r] = expf(v.x - l); Ps[m4*4+1][r] = expf(v.y - l);
      Ps[m4*4+2][r] = expf(v.z - l); Ps[m4*4+3][r] = expf(v.w - l);
    }
    #pragma unroll
    for (int i = 0; i < 8; i++){
      int t = tid + 256 * i;
      int m = t >> 5, c4 = t & 31;
      *(float4*)&Bs[m][c4 * 4] = *(const float4*)(fa + (size_t)(mm + m) * NC + c4 * 4);
    }
    __syncthreads();
    #pragma unroll 8
    for (int m = 0; m < 64; m++){
      float4 a4 = *(const float4*)&Ps[m][ty * 4];
      float4 b4 = *(const float4*)&Bs[m][tx * 4];
      acc[0][0] += a4.x*b4.x; acc[0][1] += a4.x*b4.y; acc[0][2] += a4.x*b4.z; acc[0][3] += a4.x*b4.w;
      acc[1][0] += a4.y*b4.x; acc[1][1] += a4.y*b4.y; acc[1][2] += a4.y*b4.z; acc[1][3] += a4.y*b4.w;
      acc[2][0] += a4.z*b4.x; acc[2][1] += a4.z*b4.y; acc[2][2] += a4.z*b4.z; acc[2][3] += a4.z*b4.w;
      acc[3][0] += a4.w*b4.x; acc[3][1] += a4.w*b4.y; acc[3][2] += a4.w*b4.z; acc[3][3] += a4.w*b4.w;
    }
    __syncthreads();
  }
  #pragma unroll
  for (int i = 0; i < 4; i++){
    float4 o = make_float4(acc[i][0], acc[i][1], acc[i][2], acc[i][3]);
    *(float4*)(fvaH + ((size_t)(b * NN + n0 + ty * 4 + i)) * NC + tx * 4) = o;
  }
}

// ---- quantize L2 = M*INV_TAU*LOG2E to int16 + transposed copy
__global__ __launch_bounds__(256) void k_quant_t(const float* __restrict__ Mb,
                                                 const float* __restrict__ accs,
                                                 short* __restrict__ Q,
                                                 short* __restrict__ Qt){
  __shared__ float T[64][68];
  float KQ = (INV_TAU * LOG2E) / accs[80];
  int b = blockIdx.z; int n0 = blockIdx.y * 64, m0 = blockIdx.x * 64;
  const float* src = Mb + (size_t)b * NN * NN;
  int tid = threadIdx.x;
  #pragma unroll
  for (int i = 0; i < 4; i++){
    int t = tid + 256 * i; int r = t >> 4, c4 = t & 15;
    float4 v = *(const float4*)(src + (size_t)(n0 + r) * NN + m0 + c4 * 4);
    float q0 = rintf(v.x * KQ);
    float q1 = rintf(v.y * KQ);
    float q2 = rintf(v.z * KQ);
    float q3 = rintf(v.w * KQ);
    T[r][c4*4+0] = q0; T[r][c4*4+1] = q1; T[r][c4*4+2] = q2; T[r][c4*4+3] = q3;
    int2 w;
    w.x = ((int)q0 & 0xFFFF) | ((int)q1 << 16);
    w.y = ((int)q2 & 0xFFFF) | ((int)q3 << 16);
    *(int2*)(Q + ((size_t)(b * NN + n0 + r) * NN + m0 + c4 * 4)) = w;
  }
  __syncthreads();
  #pragma unroll
  for (int i = 0; i < 4; i++){
    int t = tid + 256 * i; int r = t >> 4, c4 = t & 15;
    float q0 = T[c4*4+0][r], q1 = T[c4*4+1][r], q2 = T[c4*4+2][r], q3 = T[c4*4+3][r];
    int2 w;
    w.x = ((int)q0 & 0xFFFF) | ((int)q1 << 16);
    w.y = ((int)q2 & 0xFFFF) | ((int)q3 << 16);
    *(int2*)(Qt + ((size_t)(b * NN + m0 + r) * NN + n0 + c4 * 4)) = w;
  }
}

// ---- fused sinkhorn: 30 iterations, grid-synced; rows held dequantized in registers.
// log2 domain: P2[i] = -LSE2_j(L2[i,j] + V2[j]), V2[j] = -LSE2_i(L2t[j,i] + P2[i])
__global__ __launch_bounds__(1024) void k_sinkhorn(const short* __restrict__ Q,
                                                   const short* __restrict__ Qt,
                                                   float* __restrict__ P2,
                                                   float* __restrict__ V2,
                                                   float* __restrict__ accs){
  cg::grid_group grid = cg::this_grid();
  __shared__ float red[16];
  __shared__ float bflag;
  const float IQ2 = accs[80];
  int tid = threadIdx.x, wid = tid >> 6, lane = tid & 63;
  int blk = blockIdx.x;            // 256 blocks, 32 rows each
  int b = blk >> 5;                // batch (32 blocks per batch)
  int row0 = blk * 32 + wid * 2;   // 2 rows per wave
  // hoist + dequantize this wave's rows (once, reused 30 iterations)
  float Lq[2][16], Lt[2][16];
  #pragma unroll
  for (int r = 0; r < 2; r++){
    const int4* qa = (const int4*)(Q + (size_t)(row0 + r) * NN);
    int4 wa = qa[lane], wb = qa[64 + lane];
    int qq[8] = { wa.x, wa.y, wa.z, wa.w, wb.x, wb.y, wb.z, wb.w };
    #pragma unroll
    for (int k = 0; k < 8; k++){
      Lq[r][2*k]   = (float)(short)(qq[k]) * IQ2;
      Lq[r][2*k+1] = (float)(qq[k] >> 16)  * IQ2;
    }
    const int4* qb = (const int4*)(Qt + (size_t)(row0 + r) * NN);
    int4 ta = qb[lane], tb = qb[64 + lane];
    int tt[8] = { ta.x, ta.y, ta.z, ta.w, tb.x, tb.y, tb.z, tb.w };
    #pragma unroll
    for (int k = 0; k < 8; k++){
      Lt[r][2*k]   = (float)(short)(tt[k]) * IQ2;
      Lt[r][2*k+1] = (float)(tt[k] >> 16)  * IQ2;
    }
  }
  const float* Vb = V2 + b * NN;
  const float* Pb = P2 + b * NN;
  for (int it = 0; it < 30; it++){
    // ---- row pass -> P2
    float hh[16];
    load16(Vb, lane, hh);
    float dmax = 0.0f;
    #pragma unroll
    for (int r = 0; r < 2; r++){
      float mx = -3.402823466e38f;
      #pragma unroll
      for (int k = 0; k < 16; k++) mx = fmaxf(mx, Lq[r][k] + hh[k]);
      mx = wmax(mx);
      float s = 0.0f;
      #pragma unroll
      for (int k = 0; k < 16; k++) s += fexp2(Lq[r][k] + hh[k] - mx);
      s = wsum(s);
      if (lane == 0){
        float nv = -(mx + flog2(s));
        dmax = fmaxf(dmax, fabsf(nv - P2[row0 + r]));
        P2[row0 + r] = nv;
      }
    }
    if (lane == 0) red[wid] = dmax;
    __syncthreads();
    if (tid == 0){
      float d = red[0];
      #pragma unroll
      for (int i = 1; i < 16; i++) d = fmaxf(d, red[i]);
      atomicMax((int*)&accs[96 + it], __float_as_int(d));
    }
    __threadfence();
    grid.sync();
    // ---- col pass -> V2
    float pp[16];
    load16(Pb, lane, pp);
    #pragma unroll
    for (int r = 0; r < 2; r++){
      float mx = -3.402823466e38f;
      #pragma unroll
      for (int k = 0; k < 16; k++) mx = fmaxf(mx, Lt[r][k] + pp[k]);
      mx = wmax(mx);
      float s = 0.0f;
      #pragma unroll
      for (int k = 0; k < 16; k++) s += fexp2(Lt[r][k] + pp[k] - mx);
      s = wsum(s);
      if (lane == 0) V2[row0 + r] = -(mx + flog2(s));
    }
    if (tid == 0) bflag = __int_as_float(atomicMax((int*)&accs[96 + it], 0));
    __threadfence();
    grid.sync();
    if (bflag < SINK_EPS) break;   // uniform across grid (same accs value everywhere)
  }
}

// ---- fused final reduction (log2 domain, pc in padded LDS): loss, Lc, perm_to_I
__global__ __launch_bounds__(1024) void k_final(const short* __restrict__ Q,
                                                const short* __restrict__ Q12,
                                                const float* __restrict__ lse2,
                                                const float* __restrict__ P2,
                                                const float* __restrict__ V2,
                                                const float* __restrict__ pc0,
                                                float* __restrict__ accs){
  __shared__ float pcx[1152], pcy[1152], pcz[1152];
  __shared__ float partial[3][16];
  const float IQ2 = accs[80];
  const float IQ12_2 = (400.0f / 32766.0f) * LOG2E;
  int tid = threadIdx.x, wid = tid >> 6, lane = tid & 63;
  int row = blockIdx.x * 16 + wid;     // grid 512
  int b = row >> 10, n = row & 1023;
  {
    int m = tid;                        // 1024 threads = 1024 points
    const float* pg = pc0 + (size_t)b * 3072 + 3 * m;
    float px = pg[0], py = pg[1], pz = pg[2];
    int idx = m + (m >> 3);             // pad: bank=(9L+k)%32 -> 2-way (free)
    pcx[idx] = px; pcy[idx] = py; pcz[idx] = pz;
  }
  __syncthreads();
  const int4* qp  = (const int4*)(Q   + (size_t)row * NN);
  const int4* qp2 = (const int4*)(Q12 + (size_t)row * NN);
  int4 a1 = qp[lane],  b1 = qp[64 + lane];
  int4 a2 = qp2[lane], b2 = qp2[64 + lane];
  int q1[8] = { a1.x, a1.y, a1.z, a1.w, b1.x, b1.y, b1.z, b1.w };
  int q2[8] = { a2.x, a2.y, a2.z, a2.w, b2.x, b2.y, b2.z, b2.w };
  float L[16], c[16];
  float cmx = -3.402823466e38f;
  #pragma unroll
  for (int k = 0; k < 8; k++){
    L[2*k]   = (float)(short)(q1[k]) * IQ2;
    L[2*k+1] = (float)(q1[k] >> 16)  * IQ2;
    c[2*k]   = (float)(short)(q2[k]) * IQ12_2;
    c[2*k+1] = (float)(q2[k] >> 16)  * IQ12_2;
    cmx = fmaxf(cmx, fmaxf(c[2*k], c[2*k+1]));
  }
  cmx = wmax(cmx);
  float cs = 0.0f;
  #pragma unroll
  for (int k = 0; k < 16; k++) cs += fexp2(c[k] - cmx);
  cs = wsum(cs);
  float lse12r = cmx + flog2(cs);
  float vv[16];
  load16(V2 + b * NN, lane, vv);
  int nidx = n + (n >> 3);
  float qx = pcx[nidx], qy = pcy[nidx], qz = pcz[nidx];
  float c1row = -lse2[row] * LOG2E;
  float Prow = P2[row];
  float sl = 0.0f, slc = 0.0f, spi = 0.0f;
  #pragma unroll
  for (int k = 0; k < 16; k++){
    int m = (k < 8) ? (8 * lane + k) : (512 + 8 * lane + k - 8);
    int midx = m + (m >> 3);
    float e1 = fexp2(fmaf(L[k], 0.3f, c1row));
    float sk = fexp2(L[k] + Prow + vv[k]);
    float e2 = fexp2(c[k] - lse12r);
    float dx = qx - pcx[midx], dy = qy - pcy[midx], dz = qz - pcz[midx];
    float d = sqrtf(sqrtf(dx*dx + dy*dy + dz*dz));
    sl  += d * (e1 + e2);
    slc += fabsf(sk - e1);
    spi += fabsf(((m == n) ? 1.0f : 0.0f) - sk);
  }
  sl = wsum(sl); slc = wsum(slc); spi = wsum(spi);
  if (lane == 0){ partial[0][wid] = sl; partial[1][wid] = slc; partial[2][wid] = spi; }
  __syncthreads();
  if (tid < 3){
    float t = 0.0f;
    #pragma unroll
    for (int i = 0; i < 16; i++) t += partial[tid][i];
    atomicAdd(&accs[tid * 16 + (blockIdx.x & 15)], t);
  }
}

__global__ void k_finalize(const float* __restrict__ accs, float* __restrict__ out){
  if (threadIdx.x == 0){
    float sl = 0, slc = 0, spi = 0, scm = 0;
    for (int j = 0; j < 16; j++){
      sl += accs[j]; slc += accs[16 + j]; spi += accs[32 + j]; scm += accs[48 + j];
    }
    float loss = sl / 1024.0f;
    float Lc   = 3.0f * slc / 1024.0f;
    float perm = 3.0f * spi / 1024.0f;
    float total = loss + Lc;
    out[0] = total / 8.0f;
    out[1] = loss / 8.0f;
    out[2] = Lc / 8.0f;
    out[3] = scm / 8.0f;
    out[4] = perm / 8.0f;
  }
}

extern "C" void kernel_launch(void* const* d_in, const int* in_sizes, int n_in,
                              void* d_out, int out_size, void* d_ws, size_t ws_size,
                              hipStream_t stream){
  const float* feats = (const float*)d_in[0];   // [16,1024,128]
  const float* pc0   = (const float*)d_in[1];   // [8,1024,3]
  float* out = (float*)d_out;                   // 5 scalars

  float* ws  = (float*)d_ws;
  float* f1   = ws;                    // 1,048,576 f
  float* f2   = f1  + 1048576;         // 1,048,576 f
  float* fva  = f2  + 1048576;         // 2,097,152 f (two halves)
  float* M    = fva + 2097152;         // 8,388,608 f : corr_1a -> corr_1a2
  short* Q    = (short*)(M + 8388608); // 8,388,608 s16
  short* Qt   = Q + 8388608;           // 8,388,608 s16 (later reused as Q12)
  float* lse1 = (float*)(Qt + 8388608);// 8192
  float* lse2 = lse1 + 8192;           // 8192
  float* P    = lse2 + 8192;           // 8192  (log2-domain potentials)
  float* V    = P   + 8192;            // 8192
  float* accs = V   + 8192;            // 128
  if (ws_size < (size_t)((float*)(accs + 128) - ws) * sizeof(float)) return;

  k_init<<<32, 256, 0, stream>>>(accs, V);
  k_normalize<<<16384, 64, 0, stream>>>(feats, f1, f2);
  // corr_1a = f1 @ roll(f1)^T
  k_gemm_bt<<<dim3(16,16,8), 256, 0, stream>>>(f1, f1, f1, M, 1, 0, 0);
  k_rowstats<<<2048, 256, 0, stream>>>(M, lse1);
  // f1_via_fa = softmax(corr_1a) @ roll(f1) — m-split x2
  k_fva<<<dim3(32,8,2), 256, 0, stream>>>(M, lse1, f1, fva);
  // corr_1a2 = (fvaA+fvaB) @ f2^T
  k_gemm_bt<<<dim3(16,16,8), 256, 0, stream>>>(fva, fva + 1048576, f2, M, 0, 1, 0);
  k_rowstats_argmax<<<2048, 256, 0, stream>>>(M, lse2, accs);
  k_scale<<<1, 64, 0, stream>>>(accs);
  // Q = int16(M*INV_TAU*LOG2E), Qt = transpose
  k_quant_t<<<dim3(16,16,8), 256, 0, stream>>>(M, accs, Q, Qt);
  // fused sinkhorn (cooperative, grid-synced, early-exit on convergence)
  {
    void* args[] = { (void*)&Q, (void*)&Qt, (void*)&P, (void*)&V, (void*)&accs };
    hipLaunchCooperativeKernel((const void*)(void*)k_sinkhorn, dim3(256), dim3(1024),
                               args, 0, stream);
  }
  // corr_12 = f1 @ f2^T as int16, into the now-dead Qt buffer
  k_gemm_bt<<<dim3(16,16,8), 256, 0, stream>>>(f1, f1, f2, Qt, 0, 0, 1);
  k_final<<<512, 1024, 0, stream>>>(Q, Qt, lse2, P, V, pc0, accs);
  k_finalize<<<1, 64, 0, stream>>>(accs, out);
}

// Round 6
// 546.160 us; speedup vs baseline: 11.0712x; 11.0712x over previous
//
#include <hip/hip_runtime.h>
#include <math.h>

#define NB 8
#define NN 1024
#define NC 128
#define INV_TAU (1.0f/0.3f)
#define LOG2E 1.44269504088896340736f

__device__ __forceinline__ float wsum(float v){
  #pragma unroll
  for (int o = 32; o > 0; o >>= 1) v += __shfl_xor(v, o, 64);
  return v;
}
__device__ __forceinline__ float wmax(float v){
  #pragma unroll
  for (int o = 32; o > 0; o >>= 1) v = fmaxf(v, __shfl_xor(v, o, 64));
  return v;
}
__device__ __forceinline__ float fexp2(float x){ return __builtin_amdgcn_exp2f(x); }
__device__ __forceinline__ float flog2(float x){ return __builtin_amdgcn_logf(x); }

// load 16 floats for this lane's j-slots: j = 8*lane..+8 and 512+8*lane..+8
__device__ __forceinline__ void load16(const float* __restrict__ base, int lane, float* o){
  float4 a = *(const float4*)(base + 8 * lane);
  float4 b = *(const float4*)(base + 8 * lane + 4);
  float4 c = *(const float4*)(base + 512 + 8 * lane);
  float4 d = *(const float4*)(base + 512 + 8 * lane + 4);
  o[0]=a.x; o[1]=a.y; o[2]=a.z; o[3]=a.w; o[4]=b.x; o[5]=b.y; o[6]=b.z; o[7]=b.w;
  o[8]=c.x; o[9]=c.y; o[10]=c.z; o[11]=c.w; o[12]=d.x; o[13]=d.y; o[14]=d.z; o[15]=d.w;
}

// accs: [0:16) loss | [16:32) lc | [32:48) perm | [48:64) cm | [64:80) gmax | 80 IQ2
__global__ void k_init(float* accs, float* V){
  int i = blockIdx.x * 256 + threadIdx.x;   // grid 32 x 256 = 8192
  if (i < 128) accs[i] = 0.0f;
  V[i] = 0.0f;
}

// ---- L2 normalize * 20 over C; feats[16,1024,128] -> f1 = rows 0::2, f2 = 1::2
__global__ void k_normalize(const float* __restrict__ feats,
                            float* __restrict__ f1, float* __restrict__ f2){
  int vid = blockIdx.x;
  int lane = threadIdx.x;          // 64 threads, 2 floats each
  const float* src = feats + (size_t)vid * NC;
  float2 x = *(const float2*)(src + lane * 2);
  float s = wsum(x.x * x.x + x.y * x.y);
  float sc = 20.0f / fmaxf(sqrtf(s), 1e-12f);
  int batch = vid >> 10, n = vid & 1023;
  float* dst = ((batch & 1) ? f2 : f1) + ((size_t)(batch >> 1) * NN + n) * NC;
  float2 y; y.x = x.x * sc; y.y = x.y * sc;
  *(float2*)(dst + lane * 2) = y;
}

// ---- C[b] = A[b] (1024x128) * B[(b+rollB)&7]^T -> [1024x1024]
__global__ __launch_bounds__(256) void k_gemm_bt(const float* __restrict__ A,
                                                 const float* __restrict__ A2,
                                                 const float* __restrict__ Bm,
                                                 void* __restrict__ Cm,
                                                 int rollB, int addA, int q16){
  __shared__ float As[64][68];
  __shared__ float Bs[64][68];
  const float QS12 = 32766.0f / 400.0f;
  int b = blockIdx.z;
  int n0 = blockIdx.y * 64, m0 = blockIdx.x * 64;
  const float* Ab  = A  + (size_t)b * NN * NC;
  const float* A2b = A2 + (size_t)b * NN * NC;
  const float* Bb  = Bm + (size_t)((b + rollB) & 7) * NN * NC;
  int tid = threadIdx.x;
  int ty = tid >> 4, tx = tid & 15;
  float acc[4][4] = {};
  for (int kk = 0; kk < NC; kk += 64){
    #pragma unroll
    for (int i = 0; i < 4; i++){
      int t = tid + 256 * i;
      int r = t >> 4, k4 = t & 15;
      float4 va = *(const float4*)(Ab + (size_t)(n0 + r) * NC + kk + k4 * 4);
      if (addA){
        float4 v2 = *(const float4*)(A2b + (size_t)(n0 + r) * NC + kk + k4 * 4);
        va.x += v2.x; va.y += v2.y; va.z += v2.z; va.w += v2.w;
      }
      As[k4*4+0][r] = va.x; As[k4*4+1][r] = va.y; As[k4*4+2][r] = va.z; As[k4*4+3][r] = va.w;
      float4 vb = *(const float4*)(Bb + (size_t)(m0 + r) * NC + kk + k4 * 4);
      Bs[k4*4+0][r] = vb.x; Bs[k4*4+1][r] = vb.y; Bs[k4*4+2][r] = vb.z; Bs[k4*4+3][r] = vb.w;
    }
    __syncthreads();
    #pragma unroll 8
    for (int k = 0; k < 64; k++){
      float4 a4 = *(const float4*)&As[k][ty * 4];
      float4 b4 = *(const float4*)&Bs[k][tx * 4];
      acc[0][0] += a4.x*b4.x; acc[0][1] += a4.x*b4.y; acc[0][2] += a4.x*b4.z; acc[0][3] += a4.x*b4.w;
      acc[1][0] += a4.y*b4.x; acc[1][1] += a4.y*b4.y; acc[1][2] += a4.y*b4.z; acc[1][3] += a4.y*b4.w;
      acc[2][0] += a4.z*b4.x; acc[2][1] += a4.z*b4.y; acc[2][2] += a4.z*b4.z; acc[2][3] += a4.z*b4.w;
      acc[3][0] += a4.w*b4.x; acc[3][1] += a4.w*b4.y; acc[3][2] += a4.w*b4.z; acc[3][3] += a4.w*b4.w;
    }
    __syncthreads();
  }
  if (q16){
    short* Cb = (short*)Cm + (size_t)b * NN * NN;
    #pragma unroll
    for (int i = 0; i < 4; i++){
      int qv[4];
      #pragma unroll
      for (int j = 0; j < 4; j++){
        float q = rintf(fminf(fmaxf(acc[i][j] * QS12, -32766.0f), 32766.0f));
        qv[j] = (int)q;
      }
      int2 w;
      w.x = (qv[0] & 0xFFFF) | (qv[1] << 16);
      w.y = (qv[2] & 0xFFFF) | (qv[3] << 16);
      *(int2*)(Cb + (size_t)(n0 + ty * 4 + i) * NN + m0 + tx * 4) = w;
    }
  } else {
    float* Cb = (float*)Cm + (size_t)b * NN * NN;
    #pragma unroll
    for (int i = 0; i < 4; i++){
      float4 o = make_float4(acc[i][0], acc[i][1], acc[i][2], acc[i][3]);
      *(float4*)(Cb + (size_t)(n0 + ty * 4 + i) * NN + m0 + tx * 4) = o;
    }
  }
}

// ---- per-row logsumexp (nat domain, for k_fva)
__global__ void k_rowstats(const float* __restrict__ Mb, float* __restrict__ lse){
  int row = blockIdx.x * 4 + (threadIdx.x >> 6);
  int lane = threadIdx.x & 63;
  const float* p = Mb + (size_t)row * NN;
  float x[16]; float mx = -3.402823466e38f;
  #pragma unroll
  for (int k = 0; k < 16; k++){ x[k] = p[lane + 64 * k]; mx = fmaxf(mx, x[k]); }
  mx = wmax(mx);
  float s = 0.0f;
  #pragma unroll
  for (int k = 0; k < 16; k++) s += expf(x[k] - mx);
  s = wsum(s);
  if (lane == 0) lse[row] = mx + logf(s);
}

// ---- row stats (nat) + argmax + correct_match + global absmax
__global__ void k_rowstats_argmax(const float* __restrict__ Mb, float* __restrict__ lse,
                                  float* __restrict__ accs){
  __shared__ float axs[4];
  int row = blockIdx.x * 4 + (threadIdx.x >> 6);
  int wid = threadIdx.x >> 6;
  int lane = threadIdx.x & 63;
  const float* p = Mb + (size_t)row * NN;
  float x[16]; float mx = -3.402823466e38f; float ax = 0.0f;
  float bm = -3.402823466e38f; int bi = 0;
  #pragma unroll
  for (int k = 0; k < 16; k++){
    x[k] = p[lane + 64 * k];
    mx = fmaxf(mx, x[k]);
    ax = fmaxf(ax, fabsf(x[k]));
    if (x[k] > bm){ bm = x[k]; bi = lane + 64 * k; }
  }
  mx = wmax(mx); ax = wmax(ax);
  #pragma unroll
  for (int o = 32; o > 0; o >>= 1){
    float om = __shfl_xor(bm, o, 64); int oi = __shfl_xor(bi, o, 64);
    if (om > bm || (om == bm && oi < bi)){ bm = om; bi = oi; }
  }
  float s = 0.0f;
  #pragma unroll
  for (int k = 0; k < 16; k++) s += expf(x[k] - mx);
  s = wsum(s);
  if (lane == 0){
    lse[row] = mx + logf(s);
    axs[wid] = ax;
    if (bi == (row & 1023)) atomicAdd(&accs[48 + (blockIdx.x & 15)], 1.0f);
  }
  __syncthreads();
  if (threadIdx.x == 0){
    float a = fmaxf(fmaxf(axs[0], axs[1]), fmaxf(axs[2], axs[3]));
    atomicMax((int*)&accs[64 + (blockIdx.x & 15)], __float_as_int(a));
  }
}

// ---- quantization scale: L2 = M*INV_TAU*LOG2E quantized to +-32766
__global__ void k_scale(float* accs){
  if (threadIdx.x == 0){
    float g = 0.0f;
    for (int j = 0; j < 16; j++) g = fmaxf(g, accs[64 + j]);
    accs[80] = (g * INV_TAU * LOG2E) / 32766.0f;   // IQ2
  }
}

// ---- fva_half[z][b,n,c] = sum_{m in half z} exp(M[b,n,m]-lse1[b,n]) * f1[(b+1)&7][m][c]
__global__ __launch_bounds__(256) void k_fva(const float* __restrict__ Mb,
                                             const float* __restrict__ lse1,
                                             const float* __restrict__ f1,
                                             float* __restrict__ fva){
  __shared__ float Ps[64][36];
  __shared__ float Bs[64][128];
  int b = blockIdx.y;
  int z = blockIdx.z;
  int n0 = blockIdx.x * 32;
  int mbase = z * 512;
  const float* Mrow = Mb + (size_t)(b * NN + n0) * NN + mbase;
  const float* fa = f1 + (size_t)((b + 1) & 7) * NN * NC + (size_t)mbase * NC;
  const float* lseb = lse1 + b * NN + n0;
  float* fvaH = fva + (size_t)z * 1048576;
  int tid = threadIdx.x;
  int ty = tid >> 5, tx = tid & 31;
  float acc[4][4] = {};
  for (int mm = 0; mm < 512; mm += 64){
    #pragma unroll
    for (int i = 0; i < 2; i++){
      int t = tid + 256 * i;
      int r = t >> 4, m4 = t & 15;
      float l = lseb[r];
      float4 v = *(const float4*)(Mrow + (size_t)r * NN + mm + m4 * 4);
      Ps[m4*4+0][r] = expf(v.x - l); Ps[m4*4+1][r] = expf(v.y - l);
      Ps[m4*4+2][r] = expf(v.z - l); Ps[m4*4+3][r] = expf(v.w - l);
    }
    #pragma unroll
    for (int i = 0; i < 8; i++){
      int t = tid + 256 * i;
      int m = t >> 5, c4 = t & 31;
      *(float4*)&Bs[m][c4 * 4] = *(const float4*)(fa + (size_t)(mm + m) * NC + c4 * 4);
    }
    __syncthreads();
    #pragma unroll 8
    for (int m = 0; m < 64; m++){
      float4 a4 = *(const float4*)&Ps[m][ty * 4];
      float4 b4 = *(const float4*)&Bs[m][tx * 4];
      acc[0][0] += a4.x*b4.x; acc[0][1] += a4.x*b4.y; acc[0][2] += a4.x*b4.z; acc[0][3] += a4.x*b4.w;
      acc[1][0] += a4.y*b4.x; acc[1][1] += a4.y*b4.y; acc[1][2] += a4.y*b4.z; acc[1][3] += a4.y*b4.w;
      acc[2][0] += a4.z*b4.x; acc[2][1] += a4.z*b4.y; acc[2][2] += a4.z*b4.z; acc[2][3] += a4.z*b4.w;
      acc[3][0] += a4.w*b4.x; acc[3][1] += a4.w*b4.y; acc[3][2] += a4.w*b4.z; acc[3][3] += a4.w*b4.w;
    }
    __syncthreads();
  }
  #pragma unroll
  for (int i = 0; i < 4; i++){
    float4 o = make_float4(acc[i][0], acc[i][1], acc[i][2], acc[i][3]);
    *(float4*)(fvaH + ((size_t)(b * NN + n0 + ty * 4 + i)) * NC + tx * 4) = o;
  }
}

// ---- quantize L2 = M*INV_TAU*LOG2E to int16 + transposed copy
__global__ __launch_bounds__(256) void k_quant_t(const float* __restrict__ Mb,
                                                 const float* __restrict__ accs,
                                                 short* __restrict__ Q,
                                                 short* __restrict__ Qt){
  __shared__ float T[64][68];
  float KQ = (INV_TAU * LOG2E) / accs[80];
  int b = blockIdx.z; int n0 = blockIdx.y * 64, m0 = blockIdx.x * 64;
  const float* src = Mb + (size_t)b * NN * NN;
  int tid = threadIdx.x;
  #pragma unroll
  for (int i = 0; i < 4; i++){
    int t = tid + 256 * i; int r = t >> 4, c4 = t & 15;
    float4 v = *(const float4*)(src + (size_t)(n0 + r) * NN + m0 + c4 * 4);
    float q0 = rintf(v.x * KQ);
    float q1 = rintf(v.y * KQ);
    float q2 = rintf(v.z * KQ);
    float q3 = rintf(v.w * KQ);
    T[r][c4*4+0] = q0; T[r][c4*4+1] = q1; T[r][c4*4+2] = q2; T[r][c4*4+3] = q3;
    int2 w;
    w.x = ((int)q0 & 0xFFFF) | ((int)q1 << 16);
    w.y = ((int)q2 & 0xFFFF) | ((int)q3 << 16);
    *(int2*)(Q + ((size_t)(b * NN + n0 + r) * NN + m0 + c4 * 4)) = w;
  }
  __syncthreads();
  #pragma unroll
  for (int i = 0; i < 4; i++){
    int t = tid + 256 * i; int r = t >> 4, c4 = t & 15;
    float q0 = T[c4*4+0][r], q1 = T[c4*4+1][r], q2 = T[c4*4+2][r], q3 = T[c4*4+3][r];
    int2 w;
    w.x = ((int)q0 & 0xFFFF) | ((int)q1 << 16);
    w.y = ((int)q2 & 0xFFFF) | ((int)q3 << 16);
    *(int2*)(Qt + ((size_t)(b * NN + m0 + r) * NN + n0 + c4 * 4)) = w;
  }
}

// ---- sinkhorn half-pass v3 (log2 domain, 1 row/wave, 2048 blocks = 32 waves/CU):
// out[i] = -LSE2_j(q[i,j]*IQ2 + in[j])
__global__ __launch_bounds__(256) void k_pass(const short* __restrict__ Q,
                                              const float* __restrict__ invec,
                                              float* __restrict__ outvec,
                                              const float* __restrict__ accs){
  const float IQ2 = accs[80];
  int tid = threadIdx.x, wid = tid >> 6, lane = tid & 63;
  int row = blockIdx.x * 4 + wid;      // 2048 blocks
  int b = row >> 10;
  float hh[16];
  load16(invec + b * NN, lane, hh);
  const int4* qp = (const int4*)(Q + (size_t)row * NN);
  int4 wa = qp[lane], wb = qp[64 + lane];
  int qq[8] = { wa.x, wa.y, wa.z, wa.w, wb.x, wb.y, wb.z, wb.w };
  float x[16]; float mx = -3.402823466e38f;
  #pragma unroll
  for (int k = 0; k < 8; k++){
    x[2*k]   = fmaf((float)(short)(qq[k]), IQ2, hh[2*k]);
    x[2*k+1] = fmaf((float)(qq[k] >> 16),  IQ2, hh[2*k+1]);
    mx = fmaxf(mx, fmaxf(x[2*k], x[2*k+1]));
  }
  mx = wmax(mx);
  float s = 0.0f;
  #pragma unroll
  for (int k = 0; k < 16; k++) s += fexp2(x[k] - mx);
  s = wsum(s);
  if (lane == 0) outvec[row] = -(mx + flog2(s));
}

// ---- fused final reduction (log2 domain, pc in padded split LDS)
__global__ __launch_bounds__(1024) void k_final(const short* __restrict__ Q,
                                                const short* __restrict__ Q12,
                                                const float* __restrict__ lse2,
                                                const float* __restrict__ P2,
                                                const float* __restrict__ V2,
                                                const float* __restrict__ pc0,
                                                float* __restrict__ accs){
  __shared__ float pcx[1152], pcy[1152], pcz[1152];
  __shared__ float partial[3][16];
  const float IQ2 = accs[80];
  const float IQ12_2 = (400.0f / 32766.0f) * LOG2E;
  int tid = threadIdx.x, wid = tid >> 6, lane = tid & 63;
  int row = blockIdx.x * 16 + wid;     // grid 512
  int b = row >> 10, n = row & 1023;
  {
    int m = tid;
    const float* pg = pc0 + (size_t)b * 3072 + 3 * m;
    float px = pg[0], py = pg[1], pz = pg[2];
    int idx = m + (m >> 3);             // bank=(9L+k)%32 -> 2-way (free)
    pcx[idx] = px; pcy[idx] = py; pcz[idx] = pz;
  }
  __syncthreads();
  const int4* qp  = (const int4*)(Q   + (size_t)row * NN);
  const int4* qp2 = (const int4*)(Q12 + (size_t)row * NN);
  int4 a1 = qp[lane],  b1 = qp[64 + lane];
  int4 a2 = qp2[lane], b2 = qp2[64 + lane];
  int q1[8] = { a1.x, a1.y, a1.z, a1.w, b1.x, b1.y, b1.z, b1.w };
  int q2[8] = { a2.x, a2.y, a2.z, a2.w, b2.x, b2.y, b2.z, b2.w };
  float L[16], c[16];
  float cmx = -3.402823466e38f;
  #pragma unroll
  for (int k = 0; k < 8; k++){
    L[2*k]   = (float)(short)(q1[k]) * IQ2;
    L[2*k+1] = (float)(q1[k] >> 16)  * IQ2;
    c[2*k]   = (float)(short)(q2[k]) * IQ12_2;
    c[2*k+1] = (float)(q2[k] >> 16)  * IQ12_2;
    cmx = fmaxf(cmx, fmaxf(c[2*k], c[2*k+1]));
  }
  cmx = wmax(cmx);
  float cs = 0.0f;
  #pragma unroll
  for (int k = 0; k < 16; k++) cs += fexp2(c[k] - cmx);
  cs = wsum(cs);
  float lse12r = cmx + flog2(cs);
  float vv[16];
  load16(V2 + b * NN, lane, vv);
  int nidx = n + (n >> 3);
  float qx = pcx[nidx], qy = pcy[nidx], qz = pcz[nidx];
  float c1row = -lse2[row] * LOG2E;
  float Prow = P2[row];
  float sl = 0.0f, slc = 0.0f, spi = 0.0f;
  #pragma unroll
  for (int k = 0; k < 16; k++){
    int m = (k < 8) ? (8 * lane + k) : (512 + 8 * lane + k - 8);
    int midx = m + (m >> 3);
    float e1 = fexp2(fmaf(L[k], 0.3f, c1row));
    float sk = fexp2(L[k] + Prow + vv[k]);
    float e2 = fexp2(c[k] - lse12r);
    float dx = qx - pcx[midx], dy = qy - pcy[midx], dz = qz - pcz[midx];
    float d = sqrtf(sqrtf(dx*dx + dy*dy + dz*dz));
    sl  += d * (e1 + e2);
    slc += fabsf(sk - e1);
    spi += fabsf(((m == n) ? 1.0f : 0.0f) - sk);
  }
  sl = wsum(sl); slc = wsum(slc); spi = wsum(spi);
  if (lane == 0){ partial[0][wid] = sl; partial[1][wid] = slc; partial[2][wid] = spi; }
  __syncthreads();
  if (tid < 3){
    float t = 0.0f;
    #pragma unroll
    for (int i = 0; i < 16; i++) t += partial[tid][i];
    atomicAdd(&accs[tid * 16 + (blockIdx.x & 15)], t);
  }
}

__global__ void k_finalize(const float* __restrict__ accs, float* __restrict__ out){
  if (threadIdx.x == 0){
    float sl = 0, slc = 0, spi = 0, scm = 0;
    for (int j = 0; j < 16; j++){
      sl += accs[j]; slc += accs[16 + j]; spi += accs[32 + j]; scm += accs[48 + j];
    }
    float loss = sl / 1024.0f;
    float Lc   = 3.0f * slc / 1024.0f;
    float perm = 3.0f * spi / 1024.0f;
    float total = loss + Lc;
    out[0] = total / 8.0f;
    out[1] = loss / 8.0f;
    out[2] = Lc / 8.0f;
    out[3] = scm / 8.0f;
    out[4] = perm / 8.0f;
  }
}

extern "C" void kernel_launch(void* const* d_in, const int* in_sizes, int n_in,
                              void* d_out, int out_size, void* d_ws, size_t ws_size,
                              hipStream_t stream){
  const float* feats = (const float*)d_in[0];   // [16,1024,128]
  const float* pc0   = (const float*)d_in[1];   // [8,1024,3]
  float* out = (float*)d_out;                   // 5 scalars

  float* ws  = (float*)d_ws;
  float* f1   = ws;                    // 1,048,576 f
  float* f2   = f1  + 1048576;         // 1,048,576 f
  float* fva  = f2  + 1048576;         // 2,097,152 f (two halves)
  float* M    = fva + 2097152;         // 8,388,608 f : corr_1a -> corr_1a2
  short* Q    = (short*)(M + 8388608); // 8,388,608 s16 (log2-scaled)
  short* Qt   = Q + 8388608;           // 8,388,608 s16 (later reused as Q12)
  float* lse1 = (float*)(Qt + 8388608);// 8192
  float* lse2 = lse1 + 8192;           // 8192
  float* P    = lse2 + 8192;           // 8192  (log2-domain potentials)
  float* V    = P   + 8192;            // 8192
  float* accs = V   + 8192;            // 128
  if (ws_size < (size_t)((float*)(accs + 128) - ws) * sizeof(float)) return;

  k_init<<<32, 256, 0, stream>>>(accs, V);
  k_normalize<<<16384, 64, 0, stream>>>(feats, f1, f2);
  // corr_1a = f1 @ roll(f1)^T
  k_gemm_bt<<<dim3(16,16,8), 256, 0, stream>>>(f1, f1, f1, M, 1, 0, 0);
  k_rowstats<<<2048, 256, 0, stream>>>(M, lse1);
  // f1_via_fa = softmax(corr_1a) @ roll(f1) — m-split x2
  k_fva<<<dim3(32,8,2), 256, 0, stream>>>(M, lse1, f1, fva);
  // corr_1a2 = (fvaA+fvaB) @ f2^T
  k_gemm_bt<<<dim3(16,16,8), 256, 0, stream>>>(fva, fva + 1048576, f2, M, 0, 1, 0);
  k_rowstats_argmax<<<2048, 256, 0, stream>>>(M, lse2, accs);
  k_scale<<<1, 64, 0, stream>>>(accs);
  // Q = int16(M*INV_TAU*LOG2E), Qt = transpose
  k_quant_t<<<dim3(16,16,8), 256, 0, stream>>>(M, accs, Q, Qt);
  // sinkhorn: 30 x (row pass -> P, col pass -> V), log2 domain
  for (int it = 0; it < 30; it++){
    k_pass<<<2048, 256, 0, stream>>>(Q,  V, P, accs);
    k_pass<<<2048, 256, 0, stream>>>(Qt, P, V, accs);
  }
  // corr_12 = f1 @ f2^T as int16, into the now-dead Qt buffer
  k_gemm_bt<<<dim3(16,16,8), 256, 0, stream>>>(f1, f1, f2, Qt, 0, 0, 1);
  k_final<<<512, 1024, 0, stream>>>(Q, Qt, lse2, P, V, pc0, accs);
  k_finalize<<<1, 64, 0, stream>>>(accs, out);
}